// Round 3
// baseline (906.594 us; speedup 1.0000x reference)
//
#include <hip/hip_runtime.h>
#include <math.h>

#define TOK_I 4096   // I
#define NE 8         // experts
#define NR 16        // lora rank
#define NQ 4096      // q out dim
#define NV 1024      // v out dim
#define LORA_SCALE 2.0f

#define BM2 128      // tokens per block, low-rank kernel
#define KB2 64       // K-chunk, low-rank kernel
#define KS  4        // K-split factor (partials summed in expand; deterministic)
#define BM3 32       // tokens per block, expand kernel

__device__ __forceinline__ void f4axpy(float4& o, float s, const float4& w) {
    o.x += s * w.x;
    o.y += s * w.y;
    o.z += s * w.z;
    o.w += s * w.w;
}

// ---------------------------------------------------------------------------
// Fallback: original fused kernel (used only if workspace is too small).
// ---------------------------------------------------------------------------
__global__ __launch_bounds__(256) void qvlora_fused_kernel(
    const float* __restrict__ h, const float* __restrict__ rw,
    const float* __restrict__ qa, const float* __restrict__ qb,
    const float* __restrict__ va, const float* __restrict__ vb,
    float* __restrict__ qout, float* __restrict__ vout)
{
    const int tok  = blockIdx.x;
    const int tid  = threadIdx.x;
    const int lane = tid & 63;
    const int wave = tid >> 6;

    __shared__ float red8[4][8];
    __shared__ float red32[4][32];
    __shared__ float sLow[32];
    __shared__ float sGate;
    __shared__ int   sSel;

    const float4* h4 = (const float4*)(h + (long)tok * TOK_I);
    float4 hreg[4];
#pragma unroll
    for (int k = 0; k < 4; ++k) hreg[k] = h4[tid + 256 * k];

    float lacc[NE];
#pragma unroll
    for (int e = 0; e < NE; ++e) lacc[e] = 0.f;
    const float4* rw4 = (const float4*)rw;
#pragma unroll
    for (int k = 0; k < 4; ++k) {
        float4 hv = hreg[k];
        int f = tid + 256 * k;
#pragma unroll
        for (int e = 0; e < NE; ++e) {
            float4 wv = rw4[e * 1024 + f];
            lacc[e] += hv.x * wv.x + hv.y * wv.y + hv.z * wv.z + hv.w * wv.w;
        }
    }
#pragma unroll
    for (int off = 32; off >= 1; off >>= 1)
#pragma unroll
        for (int e = 0; e < NE; ++e) lacc[e] += __shfl_down(lacc[e], off);
    if (lane == 0)
#pragma unroll
        for (int e = 0; e < NE; ++e) red8[wave][e] = lacc[e];
    __syncthreads();

    if (tid == 0) {
        float lg[NE];
#pragma unroll
        for (int e = 0; e < NE; ++e)
            lg[e] = red8[0][e] + red8[1][e] + red8[2][e] + red8[3][e];
        int best = 0; float mx = lg[0];
#pragma unroll
        for (int e = 1; e < NE; ++e) if (lg[e] > mx) { mx = lg[e]; best = e; }
        float s = 0.f;
#pragma unroll
        for (int e = 0; e < NE; ++e) s += __expf(lg[e] - mx);
        sSel = best; sGate = LORA_SCALE / s;
    }
    __syncthreads();

    const int e = sSel;
    float acc[32];
#pragma unroll
    for (int c = 0; c < 32; ++c) acc[c] = 0.f;
    const float4* qa4 = (const float4*)(qa + (long)e * TOK_I * NR);
    const float4* va4 = (const float4*)(va + (long)e * TOK_I * NR);
#pragma unroll
    for (int k = 0; k < 4; ++k) {
        float4 hv = hreg[k];
        float he[4] = {hv.x, hv.y, hv.z, hv.w};
        int i0 = 4 * (tid + 256 * k);
#pragma unroll
        for (int d = 0; d < 4; ++d) {
            int row4 = (i0 + d) * 4;
#pragma unroll
            for (int r4 = 0; r4 < 4; ++r4) {
                float4 wq = qa4[row4 + r4];
                float4 wv = va4[row4 + r4];
                acc[4*r4+0] += he[d]*wq.x; acc[4*r4+1] += he[d]*wq.y;
                acc[4*r4+2] += he[d]*wq.z; acc[4*r4+3] += he[d]*wq.w;
                acc[16+4*r4+0] += he[d]*wv.x; acc[16+4*r4+1] += he[d]*wv.y;
                acc[16+4*r4+2] += he[d]*wv.z; acc[16+4*r4+3] += he[d]*wv.w;
            }
        }
    }
#pragma unroll
    for (int off = 32; off >= 1; off >>= 1)
#pragma unroll
        for (int c = 0; c < 32; ++c) acc[c] += __shfl_down(acc[c], off);
    if (lane == 0)
#pragma unroll
        for (int c = 0; c < 32; ++c) red32[wave][c] = acc[c];
    __syncthreads();
    if (tid < 32) {
        float v = red32[0][tid] + red32[1][tid] + red32[2][tid] + red32[3][tid];
        sLow[tid] = v * sGate;
    }
    __syncthreads();

    float lq[NR], lv[NR];
#pragma unroll
    for (int r = 0; r < NR; ++r) { lq[r] = sLow[r]; lv[r] = sLow[16 + r]; }
    const float4* qb4 = (const float4*)(qb + (long)e * NR * NQ);
    const float4* vb4 = (const float4*)(vb + (long)e * NR * NV);
    float4* qo4 = (float4*)(qout + (long)tok * NQ);
    float4* vo4 = (float4*)(vout + (long)tok * NV);
    {
        float4 o = {0.f, 0.f, 0.f, 0.f};
#pragma unroll
        for (int r = 0; r < NR; ++r) {
            float4 w = vb4[r * 256 + tid];
            f4axpy(o, lv[r], w);
        }
        vo4[tid] = o;
    }
#pragma unroll
    for (int m = 0; m < 4; ++m) {
        float4 o = {0.f, 0.f, 0.f, 0.f};
        int f = tid + 256 * m;
#pragma unroll
        for (int r = 0; r < NR; ++r) {
            float4 w = qb4[r * 1024 + f];
            f4axpy(o, lq[r], w);
        }
        qo4[f] = o;
    }
}

// ---------------------------------------------------------------------------
// Kernel 1: router (UNCHANGED — verified selection logic, bitwise-identical
// per-token reduction). 2 tokens per 256-thread block.
// ---------------------------------------------------------------------------
__global__ __launch_bounds__(256) void router_kernel(
    const float* __restrict__ h, const float* __restrict__ rw,
    float* __restrict__ gate, int* __restrict__ tlist,
    int* __restrict__ count, int T)
{
    const int tok0 = blockIdx.x * 2;
    const int tid  = threadIdx.x;
    const int lane = tid & 63;
    const int wave = tid >> 6;

    __shared__ float red[2][4][NE];

    const float4* h4  = (const float4*)h;
    const float4* rw4 = (const float4*)rw;

    const int tA = tok0;
    const int tB = (tok0 + 1 < T) ? tok0 + 1 : tok0;   // dup-safe tail

    float4 hreg[2][4];
#pragma unroll
    for (int k = 0; k < 4; ++k) {
        hreg[0][k] = h4[(long)tA * 1024 + tid + 256 * k];
        hreg[1][k] = h4[(long)tB * 1024 + tid + 256 * k];
    }

    float lacc[2][NE];
#pragma unroll
    for (int j = 0; j < 2; ++j)
#pragma unroll
        for (int e = 0; e < NE; ++e) lacc[j][e] = 0.f;

#pragma unroll
    for (int k = 0; k < 4; ++k) {
        int f = tid + 256 * k;
        float4 h0 = hreg[0][k], h1 = hreg[1][k];
#pragma unroll
        for (int e = 0; e < NE; ++e) {
            float4 wv = rw4[e * 1024 + f];
            lacc[0][e] += h0.x*wv.x + h0.y*wv.y + h0.z*wv.z + h0.w*wv.w;
            lacc[1][e] += h1.x*wv.x + h1.y*wv.y + h1.z*wv.z + h1.w*wv.w;
        }
    }
#pragma unroll
    for (int off = 32; off >= 1; off >>= 1)
#pragma unroll
        for (int j = 0; j < 2; ++j)
#pragma unroll
            for (int e = 0; e < NE; ++e)
                lacc[j][e] += __shfl_down(lacc[j][e], off);

    if (lane == 0)
#pragma unroll
        for (int j = 0; j < 2; ++j)
#pragma unroll
            for (int e = 0; e < NE; ++e) red[j][wave][e] = lacc[j][e];
    __syncthreads();

    if (tid < 2) {
        int tk = tok0 + tid;
        if (tk < T) {
            float lg[NE];
#pragma unroll
            for (int e = 0; e < NE; ++e)
                lg[e] = red[tid][0][e] + red[tid][1][e] + red[tid][2][e] + red[tid][3][e];
            int best = 0; float mx = lg[0];
#pragma unroll
            for (int e = 1; e < NE; ++e) if (lg[e] > mx) { mx = lg[e]; best = e; }
            float s = 0.f;
#pragma unroll
            for (int e = 0; e < NE; ++e) s += __expf(lg[e] - mx);
            gate[tk] = LORA_SCALE / s;                 // max prob = 1/s
            int pos = atomicAdd(&count[best], 1);
            tlist[best * T + pos] = tk;
        }
    }
}

// ---------------------------------------------------------------------------
// Kernel 2: grouped low-rank projection, v2.
// Block (chunk, expert, k-slice): 128 tokens x 32 outputs, 128 threads,
// K range [z*1024, (z+1)*1024). Each thread: 4 tokens x 8 outputs = 32 accs.
// Per k-step: 1 ds_read_b128 (h, contiguous) + 2 broadcast ds_read_b128 (a)
// feed 32 FMAs (vs 2 LDS reads / 4 FMAs before -> ~4x less LDS pressure).
// h staged transposed via in-register 4x4 transpose + bank-balanced
// ds_write_b128 (kills the 6.35M bank-conflict cycles).
// Writes RAW partials (no gate) to lowp[z][tok][32]; expand sums + gates.
// ---------------------------------------------------------------------------
__global__ __launch_bounds__(128) void lowrank_kernel(
    const float* __restrict__ h, const float* __restrict__ qa,
    const float* __restrict__ va,
    const int* __restrict__ tlist, const int* __restrict__ count,
    float* __restrict__ lowp, int T)
{
    const int e   = blockIdx.y;
    const int cnt = count[e];
    const int m0  = blockIdx.x * BM2;
    if (m0 >= cnt) return;
    const int z   = blockIdx.z;
    const int tid = threadIdx.x;

    __shared__ float h_s[KB2][BM2 + 4];   // stride 132 floats = 33 float4
    __shared__ float a_s[KB2][32];        // [k][0..15]=qa, [16..31]=va
    __shared__ int   tl_s[BM2];

    {   // 128 threads == BM2
        int idx = m0 + tid;
        tl_s[tid] = (idx < cnt) ? tlist[e * T + idx] : -1;
    }
    __syncthreads();

    // compute-role: thread owns tokens 4*tg..4*tg+3, outputs 8*og..8*og+7
    const int tg = tid & 31;
    const int og = tid >> 5;     // 0..3
    // staging-role: kq = float4-col within K-chunk, tq = token-quad per pass
    const int kq = tid & 15;
    const int tq = tid >> 4;     // 0..7

    float4 accA0 = {0,0,0,0}, accA1 = {0,0,0,0}, accA2 = {0,0,0,0}, accA3 = {0,0,0,0};
    float4 accB0 = {0,0,0,0}, accB1 = {0,0,0,0}, accB2 = {0,0,0,0}, accB3 = {0,0,0,0};

    const float4* h4  = (const float4*)h;
    const float4* qa4 = (const float4*)(qa + (long)e * TOK_I * NR);
    const float4* va4 = (const float4*)(va + (long)e * TOK_I * NR);
    float4* h_s4 = (float4*)h_s;          // row stride 33 float4
    float4* a_s4 = (float4*)a_s;          // row stride 8 float4

    const int kbase = z * (TOK_I / KS);

    for (int k0 = kbase; k0 < kbase + TOK_I / KS; k0 += KB2) {
        // ---- stage h transposed: 4 passes x (4 row loads -> 4x4 transpose
        //      -> 4 ds_write_b128). Write banks balanced.
#pragma unroll
        for (int p = 0; p < 4; ++p) {
            int tquad = tq + 8 * p;                    // 0..31
            float4 hv0, hv1, hv2, hv3;
            {
                int t0 = tl_s[4 * tquad + 0];
                int t1 = tl_s[4 * tquad + 1];
                int t2 = tl_s[4 * tquad + 2];
                int t3 = tl_s[4 * tquad + 3];
                long cb = (long)(k0 >> 2) + kq;
                hv0 = (t0 >= 0) ? h4[(long)t0 * 1024 + cb] : make_float4(0.f,0.f,0.f,0.f);
                hv1 = (t1 >= 0) ? h4[(long)t1 * 1024 + cb] : make_float4(0.f,0.f,0.f,0.f);
                hv2 = (t2 >= 0) ? h4[(long)t2 * 1024 + cb] : make_float4(0.f,0.f,0.f,0.f);
                hv3 = (t3 >= 0) ? h4[(long)t3 * 1024 + cb] : make_float4(0.f,0.f,0.f,0.f);
            }
            h_s4[(4*kq + 0) * 33 + tquad] = make_float4(hv0.x, hv1.x, hv2.x, hv3.x);
            h_s4[(4*kq + 1) * 33 + tquad] = make_float4(hv0.y, hv1.y, hv2.y, hv3.y);
            h_s4[(4*kq + 2) * 33 + tquad] = make_float4(hv0.z, hv1.z, hv2.z, hv3.z);
            h_s4[(4*kq + 3) * 33 + tquad] = make_float4(hv0.w, hv1.w, hv2.w, hv3.w);
        }
        // ---- stage [qa|va] chunk: 4 float4 per thread, coalesced
#pragma unroll
        for (int i = 0; i < 4; ++i) {
            int lin = tid + 128 * i;                   // 0..511
            int kk  = lin >> 3;                        // 0..63
            int s   = lin & 7;                         // 0..3 qa, 4..7 va
            float4 wv = (s < 4) ? qa4[(long)(k0 + kk) * 4 + s]
                                : va4[(long)(k0 + kk) * 4 + (s - 4)];
            a_s4[kk * 8 + s] = wv;
        }
        __syncthreads();

#pragma unroll 4
        for (int k = 0; k < KB2; ++k) {
            float4 hv = h_s4[k * 33 + tg];             // 4 tokens' h at this k
            float4 a0 = a_s4[k * 8 + og * 2];          // broadcast
            float4 a1 = a_s4[k * 8 + og * 2 + 1];      // broadcast
            f4axpy(accA0, hv.x, a0); f4axpy(accB0, hv.x, a1);
            f4axpy(accA1, hv.y, a0); f4axpy(accB1, hv.y, a1);
            f4axpy(accA2, hv.z, a0); f4axpy(accB2, hv.z, a1);
            f4axpy(accA3, hv.w, a0); f4axpy(accB3, hv.w, a1);
        }
        __syncthreads();
    }

    // ---- store raw partials: lowp[(z*T + tok)*32 + 8*og .. +7]
    float4* lp4 = (float4*)lowp;
    {
        int tk = tl_s[4 * tg + 0];
        if (tk >= 0) { long b = ((long)z * T + tk) * 8 + og * 2;
                       lp4[b] = accA0; lp4[b + 1] = accB0; }
    }
    {
        int tk = tl_s[4 * tg + 1];
        if (tk >= 0) { long b = ((long)z * T + tk) * 8 + og * 2;
                       lp4[b] = accA1; lp4[b + 1] = accB1; }
    }
    {
        int tk = tl_s[4 * tg + 2];
        if (tk >= 0) { long b = ((long)z * T + tk) * 8 + og * 2;
                       lp4[b] = accA2; lp4[b + 1] = accB2; }
    }
    {
        int tk = tl_s[4 * tg + 3];
        if (tk >= 0) { long b = ((long)z * T + tk) * 8 + og * 2;
                       lp4[b] = accA3; lp4[b + 1] = accB3; }
    }
}

// ---------------------------------------------------------------------------
// Kernel 3: grouped expansion, v2. Grid z-split into 5 slices (4 q-quarters,
// 1 v) -> ~2560 active blocks (~10/CU) to hide store latency. Sums the KS
// partials (fixed order -> deterministic), applies gate, register-cached
// weight columns, coalesced float4 stores.
// ---------------------------------------------------------------------------
__global__ __launch_bounds__(256) void expand_kernel(
    const float* __restrict__ lowp, const float* __restrict__ qb,
    const float* __restrict__ vb, const float* __restrict__ gate,
    const int* __restrict__ tlist, const int* __restrict__ count,
    float* __restrict__ qout, float* __restrict__ vout, int T)
{
    const int e   = blockIdx.y;
    const int cnt = count[e];
    const int m0  = blockIdx.x * BM3;
    if (m0 >= cnt) return;
    const int z   = blockIdx.z;            // 0..3 = q quarters, 4 = v
    const int tid = threadIdx.x;

    __shared__ float ls[BM3][32];          // gated low: [0..15]=q, [16..31]=v
    __shared__ int   tl_s[BM3];

    if (tid < BM3) {
        int idx = m0 + tid;
        tl_s[tid] = (idx < cnt) ? tlist[e * T + idx] : -1;
    }
    __syncthreads();
    {
        int mm = tid >> 3, s = tid & 7;    // 32 tokens x 8 float4
        int tk = tl_s[mm];
        float4 v = {0.f, 0.f, 0.f, 0.f};
        if (tk >= 0) {
            const float4* lp4 = (const float4*)lowp;
            long b0 = ((long)0 * T + tk) * 8 + s;
            long b1 = ((long)1 * T + tk) * 8 + s;
            long b2 = ((long)2 * T + tk) * 8 + s;
            long b3 = ((long)3 * T + tk) * 8 + s;
            float4 p0 = lp4[b0], p1 = lp4[b1], p2 = lp4[b2], p3 = lp4[b3];
            float g = gate[tk];
            v.x = ((p0.x + p1.x) + (p2.x + p3.x)) * g;
            v.y = ((p0.y + p1.y) + (p2.y + p3.y)) * g;
            v.z = ((p0.z + p1.z) + (p2.z + p3.z)) * g;
            v.w = ((p0.w + p1.w) + (p2.w + p3.w)) * g;
        }
        ((float4*)ls[mm])[s] = v;
    }
    __syncthreads();

    if (z < 4) {
        int n4 = z * 256 + tid;            // float4 col within q row
        const float4* qb4 = (const float4*)(qb + (long)e * NR * NQ);
        float4 w[NR];
#pragma unroll
        for (int r = 0; r < NR; ++r) w[r] = qb4[r * 1024 + n4];
        float4* qo4 = (float4*)qout;
        for (int mm = 0; mm < BM3; ++mm) {
            int tk = tl_s[mm];
            if (tk < 0) break;             // packed list: uniform across block
            float4 o = {0.f, 0.f, 0.f, 0.f};
#pragma unroll
            for (int r = 0; r < NR; ++r) { float l = ls[mm][r]; f4axpy(o, l, w[r]); }
            qo4[(long)tk * 1024 + n4] = o;
        }
    } else {
        int n4 = tid;                      // float4 col within v row
        const float4* vb4 = (const float4*)(vb + (long)e * NR * NV);
        float4 w[NR];
#pragma unroll
        for (int r = 0; r < NR; ++r) w[r] = vb4[r * 256 + n4];
        float4* vo4 = (float4*)vout;
        for (int mm = 0; mm < BM3; ++mm) {
            int tk = tl_s[mm];
            if (tk < 0) break;
            float4 o = {0.f, 0.f, 0.f, 0.f};
#pragma unroll
            for (int r = 0; r < NR; ++r) { float l = ls[mm][16 + r]; f4axpy(o, l, w[r]); }
            vo4[(long)tk * 256 + n4] = o;
        }
    }
}

// ---------------------------------------------------------------------------
extern "C" void kernel_launch(void* const* d_in, const int* in_sizes, int n_in,
                              void* d_out, int out_size, void* d_ws, size_t ws_size,
                              hipStream_t stream) {
    const float* h  = (const float*)d_in[0];
    const float* rw = (const float*)d_in[1];
    const float* qa = (const float*)d_in[2];
    const float* qb = (const float*)d_in[3];
    const float* va = (const float*)d_in[4];
    const float* vb = (const float*)d_in[5];
    float* out = (float*)d_out;

    const int T = in_sizes[0] / TOK_I;   // 16384 tokens
    float* qout = out;
    float* vout = out + (long)T * NQ;

    // workspace layout
    size_t off_count = 0;                                  // 8 ints (256B slot)
    size_t off_gate  = 256;                                // T floats
    size_t off_tlist = off_gate + (size_t)T * 4;           // NE*T ints
    size_t off_lowp  = off_tlist + (size_t)NE * T * 4;     // KS*T*32 floats
    size_t req       = off_lowp + (size_t)KS * T * 32 * 4;

    if (ws_size < req || d_ws == nullptr) {
        // not enough workspace: previous verified single-kernel path
        qvlora_fused_kernel<<<T, 256, 0, stream>>>(h, rw, qa, qb, va, vb, qout, vout);
        return;
    }

    char*  ws    = (char*)d_ws;
    int*   count = (int*)(ws + off_count);
    float* gate  = (float*)(ws + off_gate);
    int*   tlist = (int*)(ws + off_tlist);
    float* lowp  = (float*)(ws + off_lowp);

    hipMemsetAsync(count, 0, 256, stream);
    router_kernel<<<(T + 1) / 2, 256, 0, stream>>>(h, rw, gate, tlist, count, T);
    dim3 g2((T + BM2 - 1) / BM2, NE, KS);
    lowrank_kernel<<<g2, 128, 0, stream>>>(h, qa, va, tlist, count, lowp, T);
    dim3 g3((T + BM3 - 1) / BM3, NE, 5);
    expand_kernel<<<g3, 256, 0, stream>>>(lowp, qb, vb, gate, tlist, count, qout, vout, T);
}

// Round 4
// 870.322 us; speedup vs baseline: 1.0417x; 1.0417x over previous
//
#include <hip/hip_runtime.h>
#include <math.h>

#define TOK_I 4096   // I
#define NE 8         // experts
#define NR 16        // lora rank
#define NQ 4096      // q out dim
#define NV 1024      // v out dim
#define LORA_SCALE 2.0f

#define BM2 256      // tokens per block, low-rank kernel
#define KB2 32       // K-chunk, low-rank kernel
#define KS  16       // K-split (partials in vout scratch; summed by reduce kernel)
#define BM3 32       // tokens per block, expand kernel

__device__ __forceinline__ void f4axpy(float4& o, float s, const float4& w) {
    o.x += s * w.x;
    o.y += s * w.y;
    o.z += s * w.z;
    o.w += s * w.w;
}

// ---------------------------------------------------------------------------
// Fallback: original fused kernel (used only if workspace is too small).
// ---------------------------------------------------------------------------
__global__ __launch_bounds__(256) void qvlora_fused_kernel(
    const float* __restrict__ h, const float* __restrict__ rw,
    const float* __restrict__ qa, const float* __restrict__ qb,
    const float* __restrict__ va, const float* __restrict__ vb,
    float* __restrict__ qout, float* __restrict__ vout)
{
    const int tok  = blockIdx.x;
    const int tid  = threadIdx.x;
    const int lane = tid & 63;
    const int wave = tid >> 6;

    __shared__ float red8[4][8];
    __shared__ float red32[4][32];
    __shared__ float sLow[32];
    __shared__ float sGate;
    __shared__ int   sSel;

    const float4* h4 = (const float4*)(h + (long)tok * TOK_I);
    float4 hreg[4];
#pragma unroll
    for (int k = 0; k < 4; ++k) hreg[k] = h4[tid + 256 * k];

    float lacc[NE];
#pragma unroll
    for (int e = 0; e < NE; ++e) lacc[e] = 0.f;
    const float4* rw4 = (const float4*)rw;
#pragma unroll
    for (int k = 0; k < 4; ++k) {
        float4 hv = hreg[k];
        int f = tid + 256 * k;
#pragma unroll
        for (int e = 0; e < NE; ++e) {
            float4 wv = rw4[e * 1024 + f];
            lacc[e] += hv.x * wv.x + hv.y * wv.y + hv.z * wv.z + hv.w * wv.w;
        }
    }
#pragma unroll
    for (int off = 32; off >= 1; off >>= 1)
#pragma unroll
        for (int e = 0; e < NE; ++e) lacc[e] += __shfl_down(lacc[e], off);
    if (lane == 0)
#pragma unroll
        for (int e = 0; e < NE; ++e) red8[wave][e] = lacc[e];
    __syncthreads();

    if (tid == 0) {
        float lg[NE];
#pragma unroll
        for (int e = 0; e < NE; ++e)
            lg[e] = red8[0][e] + red8[1][e] + red8[2][e] + red8[3][e];
        int best = 0; float mx = lg[0];
#pragma unroll
        for (int e = 1; e < NE; ++e) if (lg[e] > mx) { mx = lg[e]; best = e; }
        float s = 0.f;
#pragma unroll
        for (int e = 0; e < NE; ++e) s += __expf(lg[e] - mx);
        sSel = best; sGate = LORA_SCALE / s;
    }
    __syncthreads();

    const int e = sSel;
    float acc[32];
#pragma unroll
    for (int c = 0; c < 32; ++c) acc[c] = 0.f;
    const float4* qa4 = (const float4*)(qa + (long)e * TOK_I * NR);
    const float4* va4 = (const float4*)(va + (long)e * TOK_I * NR);
#pragma unroll
    for (int k = 0; k < 4; ++k) {
        float4 hv = hreg[k];
        float he[4] = {hv.x, hv.y, hv.z, hv.w};
        int i0 = 4 * (tid + 256 * k);
#pragma unroll
        for (int d = 0; d < 4; ++d) {
            int row4 = (i0 + d) * 4;
#pragma unroll
            for (int r4 = 0; r4 < 4; ++r4) {
                float4 wq = qa4[row4 + r4];
                float4 wv = va4[row4 + r4];
                acc[4*r4+0] += he[d]*wq.x; acc[4*r4+1] += he[d]*wq.y;
                acc[4*r4+2] += he[d]*wq.z; acc[4*r4+3] += he[d]*wq.w;
                acc[16+4*r4+0] += he[d]*wv.x; acc[16+4*r4+1] += he[d]*wv.y;
                acc[16+4*r4+2] += he[d]*wv.z; acc[16+4*r4+3] += he[d]*wv.w;
            }
        }
    }
#pragma unroll
    for (int off = 32; off >= 1; off >>= 1)
#pragma unroll
        for (int c = 0; c < 32; ++c) acc[c] += __shfl_down(acc[c], off);
    if (lane == 0)
#pragma unroll
        for (int c = 0; c < 32; ++c) red32[wave][c] = acc[c];
    __syncthreads();
    if (tid < 32) {
        float v = red32[0][tid] + red32[1][tid] + red32[2][tid] + red32[3][tid];
        sLow[tid] = v * sGate;
    }
    __syncthreads();

    float lq[NR], lv[NR];
#pragma unroll
    for (int r = 0; r < NR; ++r) { lq[r] = sLow[r]; lv[r] = sLow[16 + r]; }
    const float4* qb4 = (const float4*)(qb + (long)e * NR * NQ);
    const float4* vb4 = (const float4*)(vb + (long)e * NR * NV);
    float4* qo4 = (float4*)(qout + (long)tok * NQ);
    float4* vo4 = (float4*)(vout + (long)tok * NV);
    {
        float4 o = {0.f, 0.f, 0.f, 0.f};
#pragma unroll
        for (int r = 0; r < NR; ++r) {
            float4 w = vb4[r * 256 + tid];
            f4axpy(o, lv[r], w);
        }
        vo4[tid] = o;
    }
#pragma unroll
    for (int m = 0; m < 4; ++m) {
        float4 o = {0.f, 0.f, 0.f, 0.f};
        int f = tid + 256 * m;
#pragma unroll
        for (int r = 0; r < NR; ++r) {
            float4 w = qb4[r * 1024 + f];
            f4axpy(o, lq[r], w);
        }
        qo4[f] = o;
    }
}

// ---------------------------------------------------------------------------
// Kernel 1: router (UNCHANGED — verified selection logic, bitwise-identical
// per-token reduction). 2 tokens per 256-thread block.
// ---------------------------------------------------------------------------
__global__ __launch_bounds__(256) void router_kernel(
    const float* __restrict__ h, const float* __restrict__ rw,
    float* __restrict__ gate, int* __restrict__ tlist,
    int* __restrict__ count, int T)
{
    const int tok0 = blockIdx.x * 2;
    const int tid  = threadIdx.x;
    const int lane = tid & 63;
    const int wave = tid >> 6;

    __shared__ float red[2][4][NE];

    const float4* h4  = (const float4*)h;
    const float4* rw4 = (const float4*)rw;

    const int tA = tok0;
    const int tB = (tok0 + 1 < T) ? tok0 + 1 : tok0;   // dup-safe tail

    float4 hreg[2][4];
#pragma unroll
    for (int k = 0; k < 4; ++k) {
        hreg[0][k] = h4[(long)tA * 1024 + tid + 256 * k];
        hreg[1][k] = h4[(long)tB * 1024 + tid + 256 * k];
    }

    float lacc[2][NE];
#pragma unroll
    for (int j = 0; j < 2; ++j)
#pragma unroll
        for (int e = 0; e < NE; ++e) lacc[j][e] = 0.f;

#pragma unroll
    for (int k = 0; k < 4; ++k) {
        int f = tid + 256 * k;
        float4 h0 = hreg[0][k], h1 = hreg[1][k];
#pragma unroll
        for (int e = 0; e < NE; ++e) {
            float4 wv = rw4[e * 1024 + f];
            lacc[0][e] += h0.x*wv.x + h0.y*wv.y + h0.z*wv.z + h0.w*wv.w;
            lacc[1][e] += h1.x*wv.x + h1.y*wv.y + h1.z*wv.z + h1.w*wv.w;
        }
    }
#pragma unroll
    for (int off = 32; off >= 1; off >>= 1)
#pragma unroll
        for (int j = 0; j < 2; ++j)
#pragma unroll
            for (int e = 0; e < NE; ++e)
                lacc[j][e] += __shfl_down(lacc[j][e], off);

    if (lane == 0)
#pragma unroll
        for (int j = 0; j < 2; ++j)
#pragma unroll
            for (int e = 0; e < NE; ++e) red[j][wave][e] = lacc[j][e];
    __syncthreads();

    if (tid < 2) {
        int tk = tok0 + tid;
        if (tk < T) {
            float lg[NE];
#pragma unroll
            for (int e = 0; e < NE; ++e)
                lg[e] = red[tid][0][e] + red[tid][1][e] + red[tid][2][e] + red[tid][3][e];
            int best = 0; float mx = lg[0];
#pragma unroll
            for (int e = 1; e < NE; ++e) if (lg[e] > mx) { mx = lg[e]; best = e; }
            float s = 0.f;
#pragma unroll
            for (int e = 0; e < NE; ++e) s += __expf(lg[e] - mx);
            gate[tk] = LORA_SCALE / s;                 // max prob = 1/s
            int pos = atomicAdd(&count[best], 1);
            tlist[best * T + pos] = tk;
        }
    }
}

// ---------------------------------------------------------------------------
// Kernel 2: grouped low-rank projection, v3.
// Block (chunk, expert, k-slice z): 256 tokens x 32 outputs, 256 threads
// (4 waves), K-range 256 (KS=16) in 8 chunks of KB2=32.
// Compute mapping: lane = token-quad (ds_read_b128 h, 64 DISTINCT lanes,
// zero duplication), wave = output-pair (a-reads wave-UNIFORM -> broadcast).
// Per wave per k: ~24cy LDS feeds 32 FMAs (64cy) -> VALU-bound.
// Occupancy: 1024 active blocks x 4 waves, 38.4KB LDS -> 4 blocks/CU
// = 16 waves/CU. Chunk c+1 global loads issued into regs before compute(c).
// Raw partials -> part[z][tok][32] (lives in vout scratch; reduce sums).
// ---------------------------------------------------------------------------
__global__ __launch_bounds__(256, 4) void lowrank_kernel(
    const float* __restrict__ h, const float* __restrict__ qa,
    const float* __restrict__ va,
    const int* __restrict__ tlist, const int* __restrict__ count,
    float* __restrict__ part, int T)
{
    const int e   = blockIdx.y;
    const int cnt = count[e];
    const int m0  = blockIdx.x * BM2;
    if (m0 >= cnt) return;
    const int z   = blockIdx.z;
    const int tid = threadIdx.x;

    __shared__ float h_s[KB2 * (BM2 + 4)];   // [k][tok], row stride 65 float4
    __shared__ float a_s[KB2 * 32];          // [k][slot], row stride 8 float4
    __shared__ int   tl_s[BM2];

    {   // 256 threads == BM2
        int idx = m0 + tid;
        tl_s[tid] = (idx < cnt) ? tlist[e * T + idx] : -1;
    }
    __syncthreads();

    const int lane = tid & 63;   // compute: token-quad (tokens 4*lane..+3)
    const int w    = tid >> 6;   // compute: wave -> output float4 slots 2w,2w+1
    const int kq   = tid & 7;    // staging h: float4-col within chunk (8 = 32 k)
    const int tq   = tid >> 3;   // staging h: token-quad base (0..31)
    const int akk  = tid >> 3;   // staging a: k row (0..31)
    const int as   = tid & 7;    // staging a: slot (0..3 qa, 4..7 va)

    const float4* h4  = (const float4*)h;
    const float4* qa4 = (const float4*)(qa + (long)e * TOK_I * NR);
    const float4* va4 = (const float4*)(va + (long)e * TOK_I * NR);
    float4* h_s4 = (float4*)h_s;
    float4* a_s4 = (float4*)a_s;

    float4 acc0 = {0,0,0,0}, acc1 = {0,0,0,0}, acc2 = {0,0,0,0}, acc3 = {0,0,0,0};
    float4 acc4 = {0,0,0,0}, acc5 = {0,0,0,0}, acc6 = {0,0,0,0}, acc7 = {0,0,0,0};

    float4 ph[2][4];   // prefetched h rows: [pass][token j]
    float4 pa;         // prefetched a

    const int kbase = z * (TOK_I / KS);
    const int NCH   = (TOK_I / KS) / KB2;   // 8

    // prologue: load chunk 0 into regs
    {
        const int k0 = kbase;
#pragma unroll
        for (int p = 0; p < 2; ++p) {
            int tquad = tq + 32 * p;
            long cb = (long)(k0 >> 2) + kq;
            int t0 = tl_s[4*tquad+0], t1 = tl_s[4*tquad+1];
            int t2 = tl_s[4*tquad+2], t3 = tl_s[4*tquad+3];
            ph[p][0] = (t0 >= 0) ? h4[(long)t0*1024 + cb] : make_float4(0.f,0.f,0.f,0.f);
            ph[p][1] = (t1 >= 0) ? h4[(long)t1*1024 + cb] : make_float4(0.f,0.f,0.f,0.f);
            ph[p][2] = (t2 >= 0) ? h4[(long)t2*1024 + cb] : make_float4(0.f,0.f,0.f,0.f);
            ph[p][3] = (t3 >= 0) ? h4[(long)t3*1024 + cb] : make_float4(0.f,0.f,0.f,0.f);
        }
        pa = (as < 4) ? qa4[(long)(k0 + akk)*4 + as] : va4[(long)(k0 + akk)*4 + (as - 4)];
    }

    for (int c = 0; c < NCH; ++c) {
        __syncthreads();   // previous chunk's compute done -> LDS reusable
        // in-register 4x4 transpose -> bank-balanced ds_write_b128
#pragma unroll
        for (int p = 0; p < 2; ++p) {
            int tquad = tq + 32 * p;
            h_s4[(4*kq + 0)*65 + tquad] = make_float4(ph[p][0].x, ph[p][1].x, ph[p][2].x, ph[p][3].x);
            h_s4[(4*kq + 1)*65 + tquad] = make_float4(ph[p][0].y, ph[p][1].y, ph[p][2].y, ph[p][3].y);
            h_s4[(4*kq + 2)*65 + tquad] = make_float4(ph[p][0].z, ph[p][1].z, ph[p][2].z, ph[p][3].z);
            h_s4[(4*kq + 3)*65 + tquad] = make_float4(ph[p][0].w, ph[p][1].w, ph[p][2].w, ph[p][3].w);
        }
        a_s4[akk*8 + as] = pa;
        __syncthreads();

        // prefetch next chunk into regs (latency hides under compute below)
        if (c + 1 < NCH) {
            const int k0 = kbase + (c + 1) * KB2;
#pragma unroll
            for (int p = 0; p < 2; ++p) {
                int tquad = tq + 32 * p;
                long cb = (long)(k0 >> 2) + kq;
                int t0 = tl_s[4*tquad+0], t1 = tl_s[4*tquad+1];
                int t2 = tl_s[4*tquad+2], t3 = tl_s[4*tquad+3];
                ph[p][0] = (t0 >= 0) ? h4[(long)t0*1024 + cb] : make_float4(0.f,0.f,0.f,0.f);
                ph[p][1] = (t1 >= 0) ? h4[(long)t1*1024 + cb] : make_float4(0.f,0.f,0.f,0.f);
                ph[p][2] = (t2 >= 0) ? h4[(long)t2*1024 + cb] : make_float4(0.f,0.f,0.f,0.f);
                ph[p][3] = (t3 >= 0) ? h4[(long)t3*1024 + cb] : make_float4(0.f,0.f,0.f,0.f);
            }
            pa = (as < 4) ? qa4[(long)(k0 + akk)*4 + as] : va4[(long)(k0 + akk)*4 + (as - 4)];
        }

#pragma unroll 4
        for (int k = 0; k < KB2; ++k) {
            float4 hv = h_s4[k*65 + lane];        // 64 distinct lanes, min-cycles
            float4 a0 = a_s4[k*8 + 2*w];          // wave-uniform -> broadcast
            float4 a1 = a_s4[k*8 + 2*w + 1];      // wave-uniform -> broadcast
            f4axpy(acc0, hv.x, a0); f4axpy(acc1, hv.x, a1);
            f4axpy(acc2, hv.y, a0); f4axpy(acc3, hv.y, a1);
            f4axpy(acc4, hv.z, a0); f4axpy(acc5, hv.z, a1);
            f4axpy(acc6, hv.w, a0); f4axpy(acc7, hv.w, a1);
        }
    }

    // store raw partials: part[(z*T + tok)*32 + 8*... ] (float4 slots 2w, 2w+1)
    float4* pp4 = (float4*)part;
    {
        int tk = tl_s[4*lane + 0];
        if (tk >= 0) { long b = ((long)z * T + tk) * 8 + 2*w; pp4[b] = acc0; pp4[b+1] = acc1; }
    }
    {
        int tk = tl_s[4*lane + 1];
        if (tk >= 0) { long b = ((long)z * T + tk) * 8 + 2*w; pp4[b] = acc2; pp4[b+1] = acc3; }
    }
    {
        int tk = tl_s[4*lane + 2];
        if (tk >= 0) { long b = ((long)z * T + tk) * 8 + 2*w; pp4[b] = acc4; pp4[b+1] = acc5; }
    }
    {
        int tk = tl_s[4*lane + 3];
        if (tk >= 0) { long b = ((long)z * T + tk) * 8 + 2*w; pp4[b] = acc6; pp4[b+1] = acc7; }
    }
}

// ---------------------------------------------------------------------------
// Kernel 2.5: reduce partials over z (fixed ascending order -> deterministic)
// and apply gate. part (vout scratch) -> low (ws). Fully coalesced.
// ---------------------------------------------------------------------------
__global__ __launch_bounds__(256) void reduce_kernel(
    const float* __restrict__ part, const float* __restrict__ gate,
    float* __restrict__ low, int T)
{
    long idx = (long)blockIdx.x * 256 + threadIdx.x;   // over T*8 float4s
    if (idx >= (long)T * 8) return;
    const float4* p4 = (const float4*)part;
    const long stride = (long)T * 8;
    float4 a = {0.f, 0.f, 0.f, 0.f};
#pragma unroll
    for (int zz = 0; zz < KS; ++zz) {
        float4 p = p4[(long)zz * stride + idx];
        a.x += p.x; a.y += p.y; a.z += p.z; a.w += p.w;
    }
    float g = gate[idx >> 3];
    a.x *= g; a.y *= g; a.z *= g; a.w *= g;
    ((float4*)low)[idx] = a;
}

// ---------------------------------------------------------------------------
// Kernel 3: grouped expansion, v3. Same z-split (4 q-quarters + 1 v).
// low values fetched via wave-uniform SCALAR loads (readfirstlane -> s_load):
// zero LDS traffic in the inner loop, FMAs are v_fmac(v, s, v).
// ---------------------------------------------------------------------------
__global__ __launch_bounds__(256) void expand_kernel(
    const float* __restrict__ low, const float* __restrict__ qb,
    const float* __restrict__ vb,
    const int* __restrict__ tlist, const int* __restrict__ count,
    float* __restrict__ qout, float* __restrict__ vout, int T)
{
    const int e   = blockIdx.y;
    const int cnt = count[e];
    const int m0  = blockIdx.x * BM3;
    if (m0 >= cnt) return;
    const int z   = blockIdx.z;            // 0..3 = q quarters, 4 = v
    const int tid = threadIdx.x;

    __shared__ int tl_s[BM3];
    if (tid < BM3) {
        int idx = m0 + tid;
        tl_s[tid] = (idx < cnt) ? tlist[e * T + idx] : -1;
    }
    __syncthreads();

    if (z < 4) {
        int n4 = z * 256 + tid;            // float4 col within q row
        const float4* qb4 = (const float4*)(qb + (long)e * NR * NQ);
        float4 wreg[NR];
#pragma unroll
        for (int r = 0; r < NR; ++r) wreg[r] = qb4[r * 1024 + n4];
        float4* qo4 = (float4*)qout;
        for (int mm = 0; mm < BM3; ++mm) {
            int tk = __builtin_amdgcn_readfirstlane(tl_s[mm]);
            if (tk < 0) break;             // packed list: uniform across block
            const float* lw = low + (long)tk * 32;   // scalar (s_load) path
            float4 o = {0.f, 0.f, 0.f, 0.f};
#pragma unroll
            for (int r = 0; r < NR; ++r) f4axpy(o, lw[r], wreg[r]);
            qo4[(long)tk * 1024 + n4] = o;
        }
    } else {
        int n4 = tid;                      // float4 col within v row
        const float4* vb4 = (const float4*)(vb + (long)e * NR * NV);
        float4 wreg[NR];
#pragma unroll
        for (int r = 0; r < NR; ++r) wreg[r] = vb4[r * 256 + n4];
        float4* vo4 = (float4*)vout;
        for (int mm = 0; mm < BM3; ++mm) {
            int tk = __builtin_amdgcn_readfirstlane(tl_s[mm]);
            if (tk < 0) break;
            const float* lw = low + (long)tk * 32 + 16;
            float4 o = {0.f, 0.f, 0.f, 0.f};
#pragma unroll
            for (int r = 0; r < NR; ++r) f4axpy(o, lw[r], wreg[r]);
            vo4[(long)tk * 256 + n4] = o;
        }
    }
}

// ---------------------------------------------------------------------------
extern "C" void kernel_launch(void* const* d_in, const int* in_sizes, int n_in,
                              void* d_out, int out_size, void* d_ws, size_t ws_size,
                              hipStream_t stream) {
    const float* h  = (const float*)d_in[0];
    const float* rw = (const float*)d_in[1];
    const float* qa = (const float*)d_in[2];
    const float* qb = (const float*)d_in[3];
    const float* va = (const float*)d_in[4];
    const float* vb = (const float*)d_in[5];
    float* out = (float*)d_out;

    const int T = in_sizes[0] / TOK_I;   // 16384 tokens
    float* qout = out;
    float* vout = out + (long)T * NQ;

    // workspace layout (small): count, gate, tlist, low
    size_t off_count = 0;                                  // 8 ints (256B slot)
    size_t off_gate  = 256;                                // T floats
    size_t off_tlist = off_gate + (size_t)T * 4;           // NE*T ints
    size_t off_low   = off_tlist + (size_t)NE * T * 4;     // T*32 floats
    size_t req       = off_low + (size_t)T * 32 * 4;       // ~2.7 MB

    // K-split partials live in the vout region as scratch:
    // KS*T*32*4 = 33.5 MB <= T*NV*4 = 64 MB. reduce_kernel consumes them
    // before expand_kernel overwrites vout (stream-ordered).
    bool part_fits = (size_t)KS * T * 32 * 4 <= (size_t)T * NV * 4;

    if (ws_size < req || d_ws == nullptr || !part_fits) {
        // fallback: previous verified single-kernel path
        qvlora_fused_kernel<<<T, 256, 0, stream>>>(h, rw, qa, qb, va, vb, qout, vout);
        return;
    }

    char*  ws    = (char*)d_ws;
    int*   count = (int*)(ws + off_count);
    float* gate  = (float*)(ws + off_gate);
    int*   tlist = (int*)(ws + off_tlist);
    float* low   = (float*)(ws + off_low);
    float* part  = vout;                   // scratch until expand runs

    hipMemsetAsync(count, 0, 256, stream);
    router_kernel<<<(T + 1) / 2, 256, 0, stream>>>(h, rw, gate, tlist, count, T);
    dim3 g2((T + BM2 - 1) / BM2, NE, KS);
    lowrank_kernel<<<g2, 256, 0, stream>>>(h, qa, va, tlist, count, part, T);
    reduce_kernel<<<(int)(((long)T * 8 + 255) / 256), 256, 0, stream>>>(part, gate, low, T);
    dim3 g3((T + BM3 - 1) / BM3, NE, 5);
    expand_kernel<<<g3, 256, 0, stream>>>(low, qb, vb, tlist, count, qout, vout, T);
}

// Round 5
// 672.296 us; speedup vs baseline: 1.3485x; 1.2946x over previous
//
#include <hip/hip_runtime.h>
#include <math.h>

#define TOK_I 4096   // I
#define NE 8         // experts
#define NR 16        // lora rank
#define NQ 4096      // q out dim
#define NV 1024      // v out dim
#define LORA_SCALE 2.0f

#define BM2 256      // tokens per block, low-rank kernel
#define KB2 32       // K-chunk, low-rank kernel
#define KS  16       // K-split (partials in vout scratch; summed by reduce kernel)
#define BM3 32       // tokens per block, expand kernel

#define NC2MAX 72    // max lowrank chunks: T/BM2 + NE
#define NC3MAX 520   // max expand chunks:  T/BM3 + NE

__device__ __forceinline__ void f4axpy(float4& o, float s, const float4& w) {
    o.x += s * w.x;
    o.y += s * w.y;
    o.z += s * w.z;
    o.w += s * w.w;
}

// ---------------------------------------------------------------------------
// Fallback: original fused kernel (used only if workspace is too small).
// ---------------------------------------------------------------------------
__global__ __launch_bounds__(256) void qvlora_fused_kernel(
    const float* __restrict__ h, const float* __restrict__ rw,
    const float* __restrict__ qa, const float* __restrict__ qb,
    const float* __restrict__ va, const float* __restrict__ vb,
    float* __restrict__ qout, float* __restrict__ vout)
{
    const int tok  = blockIdx.x;
    const int tid  = threadIdx.x;
    const int lane = tid & 63;
    const int wave = tid >> 6;

    __shared__ float red8[4][8];
    __shared__ float red32[4][32];
    __shared__ float sLow[32];
    __shared__ float sGate;
    __shared__ int   sSel;

    const float4* h4 = (const float4*)(h + (long)tok * TOK_I);
    float4 hreg[4];
#pragma unroll
    for (int k = 0; k < 4; ++k) hreg[k] = h4[tid + 256 * k];

    float lacc[NE];
#pragma unroll
    for (int e = 0; e < NE; ++e) lacc[e] = 0.f;
    const float4* rw4 = (const float4*)rw;
#pragma unroll
    for (int k = 0; k < 4; ++k) {
        float4 hv = hreg[k];
        int f = tid + 256 * k;
#pragma unroll
        for (int e = 0; e < NE; ++e) {
            float4 wv = rw4[e * 1024 + f];
            lacc[e] += hv.x * wv.x + hv.y * wv.y + hv.z * wv.z + hv.w * wv.w;
        }
    }
#pragma unroll
    for (int off = 32; off >= 1; off >>= 1)
#pragma unroll
        for (int e = 0; e < NE; ++e) lacc[e] += __shfl_down(lacc[e], off);
    if (lane == 0)
#pragma unroll
        for (int e = 0; e < NE; ++e) red8[wave][e] = lacc[e];
    __syncthreads();

    if (tid == 0) {
        float lg[NE];
#pragma unroll
        for (int e = 0; e < NE; ++e)
            lg[e] = red8[0][e] + red8[1][e] + red8[2][e] + red8[3][e];
        int best = 0; float mx = lg[0];
#pragma unroll
        for (int e = 1; e < NE; ++e) if (lg[e] > mx) { mx = lg[e]; best = e; }
        float s = 0.f;
#pragma unroll
        for (int e = 0; e < NE; ++e) s += __expf(lg[e] - mx);
        sSel = best; sGate = LORA_SCALE / s;
    }
    __syncthreads();

    const int e = sSel;
    float acc[32];
#pragma unroll
    for (int c = 0; c < 32; ++c) acc[c] = 0.f;
    const float4* qa4 = (const float4*)(qa + (long)e * TOK_I * NR);
    const float4* va4 = (const float4*)(va + (long)e * TOK_I * NR);
#pragma unroll
    for (int k = 0; k < 4; ++k) {
        float4 hv = hreg[k];
        float he[4] = {hv.x, hv.y, hv.z, hv.w};
        int i0 = 4 * (tid + 256 * k);
#pragma unroll
        for (int d = 0; d < 4; ++d) {
            int row4 = (i0 + d) * 4;
#pragma unroll
            for (int r4 = 0; r4 < 4; ++r4) {
                float4 wq = qa4[row4 + r4];
                float4 wv = va4[row4 + r4];
                acc[4*r4+0] += he[d]*wq.x; acc[4*r4+1] += he[d]*wq.y;
                acc[4*r4+2] += he[d]*wq.z; acc[4*r4+3] += he[d]*wq.w;
                acc[16+4*r4+0] += he[d]*wv.x; acc[16+4*r4+1] += he[d]*wv.y;
                acc[16+4*r4+2] += he[d]*wv.z; acc[16+4*r4+3] += he[d]*wv.w;
            }
        }
    }
#pragma unroll
    for (int off = 32; off >= 1; off >>= 1)
#pragma unroll
        for (int c = 0; c < 32; ++c) acc[c] += __shfl_down(acc[c], off);
    if (lane == 0)
#pragma unroll
        for (int c = 0; c < 32; ++c) red32[wave][c] = acc[c];
    __syncthreads();
    if (tid < 32) {
        float v = red32[0][tid] + red32[1][tid] + red32[2][tid] + red32[3][tid];
        sLow[tid] = v * sGate;
    }
    __syncthreads();

    float lq[NR], lv[NR];
#pragma unroll
    for (int r = 0; r < NR; ++r) { lq[r] = sLow[r]; lv[r] = sLow[16 + r]; }
    const float4* qb4 = (const float4*)(qb + (long)e * NR * NQ);
    const float4* vb4 = (const float4*)(vb + (long)e * NR * NV);
    float4* qo4 = (float4*)(qout + (long)tok * NQ);
    float4* vo4 = (float4*)(vout + (long)tok * NV);
    {
        float4 o = {0.f, 0.f, 0.f, 0.f};
#pragma unroll
        for (int r = 0; r < NR; ++r) {
            float4 w = vb4[r * 256 + tid];
            f4axpy(o, lv[r], w);
        }
        vo4[tid] = o;
    }
#pragma unroll
    for (int m = 0; m < 4; ++m) {
        float4 o = {0.f, 0.f, 0.f, 0.f};
        int f = tid + 256 * m;
#pragma unroll
        for (int r = 0; r < NR; ++r) {
            float4 w = qb4[r * 1024 + f];
            f4axpy(o, lq[r], w);
        }
        qo4[f] = o;
    }
}

// ---------------------------------------------------------------------------
// Kernel 1: router (UNCHANGED — verified selection logic). 2 tokens/block.
// ---------------------------------------------------------------------------
__global__ __launch_bounds__(256) void router_kernel(
    const float* __restrict__ h, const float* __restrict__ rw,
    float* __restrict__ gate, int* __restrict__ tlist,
    int* __restrict__ count, int T)
{
    const int tok0 = blockIdx.x * 2;
    const int tid  = threadIdx.x;
    const int lane = tid & 63;
    const int wave = tid >> 6;

    __shared__ float red[2][4][NE];

    const float4* h4  = (const float4*)h;
    const float4* rw4 = (const float4*)rw;

    const int tA = tok0;
    const int tB = (tok0 + 1 < T) ? tok0 + 1 : tok0;   // dup-safe tail

    float4 hreg[2][4];
#pragma unroll
    for (int k = 0; k < 4; ++k) {
        hreg[0][k] = h4[(long)tA * 1024 + tid + 256 * k];
        hreg[1][k] = h4[(long)tB * 1024 + tid + 256 * k];
    }

    float lacc[2][NE];
#pragma unroll
    for (int j = 0; j < 2; ++j)
#pragma unroll
        for (int e = 0; e < NE; ++e) lacc[j][e] = 0.f;

#pragma unroll
    for (int k = 0; k < 4; ++k) {
        int f = tid + 256 * k;
        float4 h0 = hreg[0][k], h1 = hreg[1][k];
#pragma unroll
        for (int e = 0; e < NE; ++e) {
            float4 wv = rw4[e * 1024 + f];
            lacc[0][e] += h0.x*wv.x + h0.y*wv.y + h0.z*wv.z + h0.w*wv.w;
            lacc[1][e] += h1.x*wv.x + h1.y*wv.y + h1.z*wv.z + h1.w*wv.w;
        }
    }
#pragma unroll
    for (int off = 32; off >= 1; off >>= 1)
#pragma unroll
        for (int j = 0; j < 2; ++j)
#pragma unroll
            for (int e = 0; e < NE; ++e)
                lacc[j][e] += __shfl_down(lacc[j][e], off);

    if (lane == 0)
#pragma unroll
        for (int j = 0; j < 2; ++j)
#pragma unroll
            for (int e = 0; e < NE; ++e) red[j][wave][e] = lacc[j][e];
    __syncthreads();

    if (tid < 2) {
        int tk = tok0 + tid;
        if (tk < T) {
            float lg[NE];
#pragma unroll
            for (int e = 0; e < NE; ++e)
                lg[e] = red[tid][0][e] + red[tid][1][e] + red[tid][2][e] + red[tid][3][e];
            int best = 0; float mx = lg[0];
#pragma unroll
            for (int e = 1; e < NE; ++e) if (lg[e] > mx) { mx = lg[e]; best = e; }
            float s = 0.f;
#pragma unroll
            for (int e = 0; e < NE; ++e) s += __expf(lg[e] - mx);
            gate[tk] = LORA_SCALE / s;                 // max prob = 1/s
            int pos = atomicAdd(&count[best], 1);
            tlist[best * T + pos] = tk;
        }
    }
}

// ---------------------------------------------------------------------------
// Kernel 1.5: setup — build dense chunk maps so ALL dispatched blocks are
// active (v3's grids were 7/8 empty -> occupancy diluted to 3.4 waves/CU).
// Entry encoding: (e << 20) | m0 ; -1 = past the end.
// ---------------------------------------------------------------------------
__global__ __launch_bounds__(256) void setup_kernel(
    const int* __restrict__ count, int* __restrict__ cmap2,
    int* __restrict__ cmap3)
{
    __shared__ int pc2[NE + 1], pc3[NE + 1];
    const int tid = threadIdx.x;
    if (tid == 0) {
        int s2 = 0, s3 = 0;
        for (int e = 0; e < NE; ++e) {
            int c = count[e];
            pc2[e] = s2; pc3[e] = s3;
            s2 += (c + BM2 - 1) / BM2;
            s3 += (c + BM3 - 1) / BM3;
        }
        pc2[NE] = s2; pc3[NE] = s3;
    }
    __syncthreads();
    for (int i = tid; i < NC2MAX; i += 256) {
        int v = -1;
#pragma unroll
        for (int e = 0; e < NE; ++e)
            if (i >= pc2[e] && i < pc2[e + 1]) v = (e << 20) | ((i - pc2[e]) * BM2);
        cmap2[i] = v;
    }
    for (int i = tid; i < NC3MAX; i += 256) {
        int v = -1;
#pragma unroll
        for (int e = 0; e < NE; ++e)
            if (i >= pc3[e] && i < pc3[e + 1]) v = (e << 20) | ((i - pc3[e]) * BM3);
        cmap3[i] = v;
    }
}

// ---------------------------------------------------------------------------
// Kernel 2: grouped low-rank projection, v4.
// Same compute mapping as v3 (lane=token-quad reads contiguous b128 h,
// wave=output-pair reads broadcast a; at 4 blocks/CU this is VALU-bound:
// LDS 57.6k cy/CU < VALU 65.5k cy/CU). Fixes vs v3:
//  - cmap2: zero empty blocks -> true 4 blocks/CU (16 waves) residency
//  - branch-free staging: clamped token indices in regs, unconditional loads
//    (v3's ternary-guarded loads got sunk by the compiler: VGPR_Count=52)
//  - sched_barrier(0) pins the prefetch issue before the compute loop
// ---------------------------------------------------------------------------
__global__ __launch_bounds__(256, 4) void lowrank_kernel(
    const float* __restrict__ h, const float* __restrict__ qa,
    const float* __restrict__ va,
    const int* __restrict__ tlist, const int* __restrict__ count,
    const int* __restrict__ cmap2,
    float* __restrict__ part, int T)
{
    const int cm = cmap2[blockIdx.x];
    if (cm < 0) return;
    const int e   = cm >> 20;
    const int m0  = cm & 0xFFFFF;
    const int cnt = count[e];
    const int z   = blockIdx.y;
    const int tid = threadIdx.x;

    __shared__ float h_s[KB2 * (BM2 + 4)];   // [k][tok], row stride 65 float4
    __shared__ float a_s[KB2 * 32];          // [k][slot], row stride 8 float4
    __shared__ int   tl_s[BM2];

    {   // 256 threads == BM2
        int idx = m0 + tid;
        tl_s[tid] = (idx < cnt) ? tlist[e * T + idx] : -1;
    }
    __syncthreads();

    const int lane = tid & 63;   // compute: token-quad (tokens 4*lane..+3)
    const int w    = tid >> 6;   // compute: wave -> output float4 slots 2w,2w+1
    const int kq   = tid & 7;    // staging h: float4-col within chunk
    const int tq   = tid >> 3;   // staging h: token-quad base (0..31)
    const int akk  = tid >> 3;   // staging a: k row (0..31)
    const int as   = tid & 7;    // staging a: slot (0..3 qa, 4..7 va)

    const float4* h4  = (const float4*)h;
    const float4* qa4 = (const float4*)(qa + (long)e * TOK_I * NR);
    const float4* va4 = (const float4*)(va + (long)e * TOK_I * NR);
    float4* h_s4 = (float4*)h_s;
    float4* a_s4 = (float4*)a_s;

    // branch-free token registers: clamped for loads, raw for store guards
    int st[2][4];
#pragma unroll
    for (int p = 0; p < 2; ++p) {
        int tquad = tq + 32 * p;
#pragma unroll
        for (int j = 0; j < 4; ++j) {
            int t = tl_s[4 * tquad + j];
            st[p][j] = t > 0 ? t : 0;            // v_max_i32, no branch
        }
    }
    int ct[4];
#pragma unroll
    for (int j = 0; j < 4; ++j) ct[j] = tl_s[4 * lane + j];

    // per-thread a source pointer (branch resolved once)
    const float4* ap = (as < 4) ? (qa4 + as) : (va4 + (as - 4));

    float4 acc0 = {0,0,0,0}, acc1 = {0,0,0,0}, acc2 = {0,0,0,0}, acc3 = {0,0,0,0};
    float4 acc4 = {0,0,0,0}, acc5 = {0,0,0,0}, acc6 = {0,0,0,0}, acc7 = {0,0,0,0};

    float4 ph[2][4];   // prefetched h rows
    float4 pa;         // prefetched a

    const int kbase = z * (TOK_I / KS);
    const int NCH   = (TOK_I / KS) / KB2;   // 8

    // prologue: chunk 0 loads (unconditional, batched)
    {
        const long cb = (long)(kbase >> 2) + kq;
#pragma unroll
        for (int p = 0; p < 2; ++p)
#pragma unroll
            for (int j = 0; j < 4; ++j)
                ph[p][j] = h4[(long)st[p][j] * 1024 + cb];
        pa = ap[(long)(kbase + akk) * 4];
    }

    for (int c = 0; c < NCH; ++c) {
        __syncthreads();   // prev chunk compute done; also drains prefetch
        // in-register 4x4 transpose -> bank-balanced ds_write_b128
#pragma unroll
        for (int p = 0; p < 2; ++p) {
            int tquad = tq + 32 * p;
            h_s4[(4*kq + 0)*65 + tquad] = make_float4(ph[p][0].x, ph[p][1].x, ph[p][2].x, ph[p][3].x);
            h_s4[(4*kq + 1)*65 + tquad] = make_float4(ph[p][0].y, ph[p][1].y, ph[p][2].y, ph[p][3].y);
            h_s4[(4*kq + 2)*65 + tquad] = make_float4(ph[p][0].z, ph[p][1].z, ph[p][2].z, ph[p][3].z);
            h_s4[(4*kq + 3)*65 + tquad] = make_float4(ph[p][0].w, ph[p][1].w, ph[p][2].w, ph[p][3].w);
        }
        a_s4[akk*8 + as] = pa;
        __syncthreads();

        // prefetch next chunk (branch-free; issue pinned before compute)
        if (c + 1 < NCH) {
            const int k0 = kbase + (c + 1) * KB2;
            const long cb = (long)(k0 >> 2) + kq;
#pragma unroll
            for (int p = 0; p < 2; ++p)
#pragma unroll
                for (int j = 0; j < 4; ++j)
                    ph[p][j] = h4[(long)st[p][j] * 1024 + cb];
            pa = ap[(long)(k0 + akk) * 4];
        }
        __builtin_amdgcn_sched_barrier(0);   // don't sink loads into compute

#pragma unroll 4
        for (int k = 0; k < KB2; ++k) {
            float4 hv = h_s4[k*65 + lane];        // contiguous b128, min-cycles
            float4 a0 = a_s4[k*8 + 2*w];          // wave-uniform broadcast
            float4 a1 = a_s4[k*8 + 2*w + 1];
            f4axpy(acc0, hv.x, a0); f4axpy(acc1, hv.x, a1);
            f4axpy(acc2, hv.y, a0); f4axpy(acc3, hv.y, a1);
            f4axpy(acc4, hv.z, a0); f4axpy(acc5, hv.z, a1);
            f4axpy(acc6, hv.w, a0); f4axpy(acc7, hv.w, a1);
        }
    }

    // store raw partials: part[(z*T + tok)*32 ...] (float4 slots 2w, 2w+1)
    float4* pp4 = (float4*)part;
    if (ct[0] >= 0) { long b = ((long)z * T + ct[0]) * 8 + 2*w; pp4[b] = acc0; pp4[b+1] = acc1; }
    if (ct[1] >= 0) { long b = ((long)z * T + ct[1]) * 8 + 2*w; pp4[b] = acc2; pp4[b+1] = acc3; }
    if (ct[2] >= 0) { long b = ((long)z * T + ct[2]) * 8 + 2*w; pp4[b] = acc4; pp4[b+1] = acc5; }
    if (ct[3] >= 0) { long b = ((long)z * T + ct[3]) * 8 + 2*w; pp4[b] = acc6; pp4[b+1] = acc7; }
}

// ---------------------------------------------------------------------------
// Kernel 2.5: reduce partials over z (fixed order -> deterministic) + gate.
// ---------------------------------------------------------------------------
__global__ __launch_bounds__(256) void reduce_kernel(
    const float* __restrict__ part, const float* __restrict__ gate,
    float* __restrict__ low, int T)
{
    long idx = (long)blockIdx.x * 256 + threadIdx.x;   // over T*8 float4s
    if (idx >= (long)T * 8) return;
    const float4* p4 = (const float4*)part;
    const long stride = (long)T * 8;
    float4 a = {0.f, 0.f, 0.f, 0.f};
#pragma unroll
    for (int zz = 0; zz < KS; ++zz) {
        float4 p = p4[(long)zz * stride + idx];
        a.x += p.x; a.y += p.y; a.z += p.z; a.w += p.w;
    }
    float g = gate[idx >> 3];
    a.x *= g; a.y *= g; a.z *= g; a.w *= g;
    ((float4*)low)[idx] = a;
}

// ---------------------------------------------------------------------------
// Kernel 3: grouped expansion, v4. cmap3 -> all blocks active (~2600 blocks,
// ~10/CU). Uniform trip count (sgpr) instead of sentinel break; low fetched
// via wave-uniform scalar loads (scalar pipe, off VALU/LDS).
// ---------------------------------------------------------------------------
__global__ __launch_bounds__(256) void expand_kernel(
    const float* __restrict__ low, const float* __restrict__ qb,
    const float* __restrict__ vb,
    const int* __restrict__ tlist, const int* __restrict__ count,
    const int* __restrict__ cmap3,
    float* __restrict__ qout, float* __restrict__ vout, int T)
{
    const int cm = cmap3[blockIdx.x];
    if (cm < 0) return;
    const int e   = cm >> 20;
    const int m0  = cm & 0xFFFFF;
    const int cnt = count[e];
    const int nm  = min(BM3, cnt - m0);
    const int z   = blockIdx.y;            // 0..3 = q quarters, 4 = v
    const int tid = threadIdx.x;

    __shared__ int tl_s[BM3];
    if (tid < BM3) {
        int idx = m0 + tid;
        tl_s[tid] = (idx < cnt) ? tlist[e * T + idx] : 0;
    }
    __syncthreads();

    if (z < 4) {
        int n4 = z * 256 + tid;            // float4 col within q row
        const float4* qb4 = (const float4*)(qb + (long)e * NR * NQ);
        float4 wreg[NR];
#pragma unroll
        for (int r = 0; r < NR; ++r) wreg[r] = qb4[r * 1024 + n4];
        float4* qo4 = (float4*)qout;
        for (int mm = 0; mm < nm; ++mm) {
            int tk = __builtin_amdgcn_readfirstlane(tl_s[mm]);
            const float* lw = low + (long)tk * 32;   // scalar (s_load) path
            float4 o = {0.f, 0.f, 0.f, 0.f};
#pragma unroll
            for (int r = 0; r < NR; ++r) f4axpy(o, lw[r], wreg[r]);
            qo4[(long)tk * 1024 + n4] = o;
        }
    } else {
        int n4 = tid;                      // float4 col within v row
        const float4* vb4 = (const float4*)(vb + (long)e * NR * NV);
        float4 wreg[NR];
#pragma unroll
        for (int r = 0; r < NR; ++r) wreg[r] = vb4[r * 256 + n4];
        float4* vo4 = (float4*)vout;
        for (int mm = 0; mm < nm; ++mm) {
            int tk = __builtin_amdgcn_readfirstlane(tl_s[mm]);
            const float* lw = low + (long)tk * 32 + 16;
            float4 o = {0.f, 0.f, 0.f, 0.f};
#pragma unroll
            for (int r = 0; r < NR; ++r) f4axpy(o, lw[r], wreg[r]);
            vo4[(long)tk * 256 + n4] = o;
        }
    }
}

// ---------------------------------------------------------------------------
extern "C" void kernel_launch(void* const* d_in, const int* in_sizes, int n_in,
                              void* d_out, int out_size, void* d_ws, size_t ws_size,
                              hipStream_t stream) {
    const float* h  = (const float*)d_in[0];
    const float* rw = (const float*)d_in[1];
    const float* qa = (const float*)d_in[2];
    const float* qb = (const float*)d_in[3];
    const float* va = (const float*)d_in[4];
    const float* vb = (const float*)d_in[5];
    float* out = (float*)d_out;

    const int T = in_sizes[0] / TOK_I;   // 16384 tokens
    float* qout = out;
    float* vout = out + (long)T * NQ;

    // workspace layout
    size_t off_count = 0;                                  // 8 ints (256B slot)
    size_t off_cmap2 = 256;                                // 128 ints
    size_t off_cmap3 = off_cmap2 + 512;                    // 1024 ints
    size_t off_gate  = off_cmap3 + 4096;                   // T floats
    size_t off_tlist = off_gate + (size_t)T * 4;           // NE*T ints
    size_t off_low   = off_tlist + (size_t)NE * T * 4;     // T*32 floats
    size_t req       = off_low + (size_t)T * 32 * 4;       // ~2.7 MB

    // K-split partials live in the vout region as scratch:
    // KS*T*32*4 = 33.5 MB <= T*NV*4 = 64 MB; reduce consumes before expand.
    bool part_fits = (size_t)KS * T * 32 * 4 <= (size_t)T * NV * 4;

    if (ws_size < req || d_ws == nullptr || !part_fits) {
        qvlora_fused_kernel<<<T, 256, 0, stream>>>(h, rw, qa, qb, va, vb, qout, vout);
        return;
    }

    char*  ws    = (char*)d_ws;
    int*   count = (int*)(ws + off_count);
    int*   cmap2 = (int*)(ws + off_cmap2);
    int*   cmap3 = (int*)(ws + off_cmap3);
    float* gate  = (float*)(ws + off_gate);
    int*   tlist = (int*)(ws + off_tlist);
    float* low   = (float*)(ws + off_low);
    float* part  = vout;                   // scratch until expand runs

    hipMemsetAsync(count, 0, 256, stream);
    router_kernel<<<(T + 1) / 2, 256, 0, stream>>>(h, rw, gate, tlist, count, T);
    setup_kernel<<<1, 256, 0, stream>>>(count, cmap2, cmap3);
    dim3 g2(NC2MAX, KS);
    lowrank_kernel<<<g2, 256, 0, stream>>>(h, qa, va, tlist, count, cmap2, part, T);
    reduce_kernel<<<(int)(((long)T * 8 + 255) / 256), 256, 0, stream>>>(part, gate, low, T);
    dim3 g3(NC3MAX, 5);
    expand_kernel<<<g3, 256, 0, stream>>>(low, qb, vb, tlist, count, cmap3, qout, vout, T);
}